// Round 2
// baseline (1627.142 us; speedup 1.0000x reference)
//
#include <hip/hip_runtime.h>

typedef _Float16 f16;
typedef _Float16 f16x4 __attribute__((ext_vector_type(4)));
typedef _Float16 f16x8 __attribute__((ext_vector_type(8)));
typedef float f32x4 __attribute__((ext_vector_type(4)));

#define QSCALE 0.08838834764831845f  // DK^-0.5

// ------------------------------------------------------------------
// convert fp32 -> f16 (vectorized x4)
// ------------------------------------------------------------------
__global__ __launch_bounds__(256) void cvt16_kernel(const float* __restrict__ in,
                                                    f16* __restrict__ out, int n4) {
    int i = blockIdx.x * 256 + threadIdx.x;
    if (i >= n4) return;
    f32x4 v = ((const f32x4*)in)[i];
    f16x4 h;
    h[0] = (f16)v[0]; h[1] = (f16)v[1]; h[2] = (f16)v[2]; h[3] = (f16)v[3];
    ((f16x4*)out)[i] = h;
}

// ------------------------------------------------------------------
// transpose fp32 [R][C] -> f16 [C][R]
// ------------------------------------------------------------------
__global__ __launch_bounds__(256) void transpose16_kernel(const float* __restrict__ in,
                                                          f16* __restrict__ out, int R, int C) {
    __shared__ f16 tile[64][66];
    int c0 = blockIdx.x * 64, r0 = blockIdx.y * 64;
    int tid = threadIdx.x;
#pragma unroll
    for (int i = 0; i < 16; ++i) {
        int idx = i * 256 + tid;
        int r = idx >> 6, c = idx & 63;
        tile[r][c] = (f16)in[(long)(r0 + r) * C + (c0 + c)];
    }
    __syncthreads();
#pragma unroll
    for (int i = 0; i < 16; ++i) {
        int idx = i * 256 + tid;
        int orow = idx >> 6, oc = idx & 63;
        out[(long)(c0 + orow) * R + (r0 + oc)] = tile[oc][orow];
    }
}

// ------------------------------------------------------------------
// f16 MFMA GEMM: C[m][n] = sum_k A[m][k] * Bt[n][k]
// A [M][Kd] f16 row-major, Bt [N][Kd] f16 row-major (i.e. B transposed).
// 128x128 tile, BK=64, 4 waves (2x2), XOR-swizzled LDS, reg-staged.
// ------------------------------------------------------------------
template <int F16OUT>
__global__ __launch_bounds__(256) void gemm16_kernel(const f16* __restrict__ A,
                                                     const f16* __restrict__ Bt,
                                                     void* __restrict__ Cout,
                                                     int M, int N, int Kd) {
    __shared__ f16 sA[128 * 64];
    __shared__ f16 sB[128 * 64];
    const int tid = threadIdx.x;
    const int lane = tid & 63, wv = tid >> 6;
    const int wm = wv >> 1, wn = wv & 1;
    const int m0 = blockIdx.y * 128, n0 = blockIdx.x * 128;
    const int lrow = lane & 15, lk = lane >> 4;
    f32x4 acc[4][4] = {};
    for (int k0 = 0; k0 < Kd; k0 += 64) {
        __syncthreads();
#pragma unroll
        for (int j = 0; j < 4; ++j) {
            int P = (tid + j * 256) * 16;        // linear byte offset in 16KB tile
            int row = P >> 7;                    // tile row (128B per row)
            int sw = P ^ ((row & 7) << 4);       // swizzled LDS byte offset
            int koff = P & 127;                  // k-byte offset within row
            const char* ga = (const char*)(A + (long)(m0 + row) * Kd + k0) + koff;
            *(f32x4*)((char*)sA + sw) = *(const f32x4*)ga;
            const char* gb = (const char*)(Bt + (long)(n0 + row) * Kd + k0) + koff;
            *(f32x4*)((char*)sB + sw) = *(const f32x4*)gb;
        }
        __syncthreads();
#pragma unroll
        for (int kk = 0; kk < 2; ++kk) {
            f16x8 af[4], bf[4];
#pragma unroll
            for (int i = 0; i < 4; ++i) {
                int arow = wm * 64 + i * 16 + lrow;
                int abyte = arow * 128 + kk * 64 + lk * 16;
                af[i] = *(const f16x8*)((const char*)sA + (abyte ^ ((arow & 7) << 4)));
                int brow = wn * 64 + i * 16 + lrow;
                int bbyte = brow * 128 + kk * 64 + lk * 16;
                bf[i] = *(const f16x8*)((const char*)sB + (bbyte ^ ((brow & 7) << 4)));
            }
#pragma unroll
            for (int i = 0; i < 4; ++i)
#pragma unroll
                for (int j = 0; j < 4; ++j)
                    acc[i][j] = __builtin_amdgcn_mfma_f32_16x16x32_f16(af[i], bf[j], acc[i][j], 0, 0, 0);
        }
    }
#pragma unroll
    for (int i = 0; i < 4; ++i) {
        int gm_base = m0 + wm * 64 + i * 16 + lk * 4;
#pragma unroll
        for (int j = 0; j < 4; ++j) {
            int gn = n0 + wn * 64 + j * 16 + lrow;
#pragma unroll
            for (int r = 0; r < 4; ++r) {
                long idx = (long)(gm_base + r) * N + gn;
                if (F16OUT) ((f16*)Cout)[idx] = (f16)acc[i][j][r];
                else        ((float*)Cout)[idx] = acc[i][j][r];
            }
        }
    }
}

// ------------------------------------------------------------------
// ba = x @ w_ba   (fp32; x [4096][2048], w [2048][64] -> ba [4096][64])
// ------------------------------------------------------------------
__global__ __launch_bounds__(256) void ba_gemm_kernel(const float* __restrict__ x,
                                                      const float* __restrict__ w,
                                                      float* __restrict__ ba) {
    __shared__ float xs[16][256];
    int tid = threadIdx.x;
    int t0 = blockIdx.x * 16;
    int o = tid & 63, tg = tid >> 6;
    float acc[4] = {0.f, 0.f, 0.f, 0.f};
    for (int kc = 0; kc < 2048; kc += 256) {
        __syncthreads();
#pragma unroll
        for (int i = 0; i < 16; ++i) {
            int idx = i * 256 + tid;
            int tok = idx >> 8, k = idx & 255;
            xs[tok][k] = x[(long)(t0 + tok) * 2048 + kc + k];
        }
        __syncthreads();
        for (int k = 0; k < 256; ++k) {
            float wv = w[(long)(kc + k) * 64 + o];
#pragma unroll
            for (int j = 0; j < 4; ++j) acc[j] += xs[tg * 4 + j][k] * wv;
        }
    }
#pragma unroll
    for (int j = 0; j < 4; ++j) ba[(long)(t0 + tg * 4 + j) * 64 + o] = acc[j];
}

// ------------------------------------------------------------------
// depthwise causal conv(K=4) + bias + SiLU (+ L2norm for q/k heads)
// outputs f16
// ------------------------------------------------------------------
__global__ __launch_bounds__(256) void conv_kernel(const f16* __restrict__ qkvz,
                                                   const float* __restrict__ cw,
                                                   const float* __restrict__ cb,
                                                   f16* __restrict__ qh,
                                                   f16* __restrict__ kh,
                                                   f16* __restrict__ vh) {
    __shared__ float Lin[35 * 128];
    __shared__ float Lout[32 * 128];
    __shared__ float Lsc[32];
    int g = blockIdx.x;
    int s0 = blockIdx.y * 32;
    int b = blockIdx.z;
    int tid = threadIdx.x;
    int colbase, chbase;
    f16* outp;
    bool donorm;
    float nmul;
    if (g < 16) {
        colbase = g * 768; chbase = g * 128;
        outp = qh + (((long)b * 16 + g) * 2048 + s0) * 128;
        donorm = true; nmul = QSCALE;
    } else if (g < 32) {
        int hk = g - 16;
        colbase = hk * 768 + 128; chbase = 2048 + hk * 128;
        outp = kh + (((long)b * 16 + hk) * 2048 + s0) * 128;
        donorm = true; nmul = 1.f;
    } else {
        int hv = g - 32;
        colbase = (hv >> 1) * 768 + 256 + (hv & 1) * 128; chbase = 4096 + hv * 128;
        outp = vh + (((long)b * 32 + hv) * 2048 + s0) * 128;
        donorm = false; nmul = 1.f;
    }
    for (int idx = tid; idx < 35 * 128; idx += 256) {
        int sr = idx >> 7, c = idx & 127;
        int s = s0 + sr - 3;
        Lin[idx] = (s >= 0) ? (float)qkvz[((long)b * 2048 + s) * 12288 + colbase + c] : 0.f;
    }
    __syncthreads();
    int c = tid & 127, sg = tid >> 7;
    float w0 = cw[(chbase + c) * 4 + 0];
    float w1 = cw[(chbase + c) * 4 + 1];
    float w2 = cw[(chbase + c) * 4 + 2];
    float w3 = cw[(chbase + c) * 4 + 3];
    float bias = cb[chbase + c];
#pragma unroll
    for (int j = 0; j < 16; ++j) {
        int sl = sg * 16 + j;
        float v = w0 * Lin[sl * 128 + c] + w1 * Lin[(sl + 1) * 128 + c] +
                  w2 * Lin[(sl + 2) * 128 + c] + w3 * Lin[(sl + 3) * 128 + c] + bias;
        v = v / (1.f + expf(-v));  // SiLU
        Lout[sl * 128 + c] = v;
    }
    __syncthreads();
    if (donorm) {
        int token = tid >> 3, part = tid & 7;
        float ss = 0.f;
#pragma unroll
        for (int i = 0; i < 16; ++i) {
            float v = Lout[token * 128 + part * 16 + i];
            ss += v * v;
        }
        ss += __shfl_xor(ss, 1); ss += __shfl_xor(ss, 2); ss += __shfl_xor(ss, 4);
        if (part == 0) Lsc[token] = rsqrtf(ss + 1e-6f) * nmul;
        __syncthreads();
#pragma unroll
        for (int j = 0; j < 16; ++j) {
            int sl = sg * 16 + j;
            outp[(long)sl * 128 + c] = (f16)(Lout[sl * 128 + c] * Lsc[sl]);
        }
    } else {
#pragma unroll
        for (int j = 0; j < 16; ++j) {
            int sl = sg * 16 + j;
            outp[(long)sl * 128 + c] = (f16)Lout[sl * 128 + c];
        }
    }
}

// ------------------------------------------------------------------
// eg = exp(g), beta = sigmoid(b)  per (b,hv,s)
// ------------------------------------------------------------------
__global__ __launch_bounds__(256) void gb_kernel(const float* __restrict__ ba,
                                                 const float* __restrict__ a_log,
                                                 const float* __restrict__ dt_bias,
                                                 float* __restrict__ eg,
                                                 float* __restrict__ bt) {
    int idx = blockIdx.x * 256 + threadIdx.x;  // ((b*32+hv)*2048 + s)
    if (idx >= 2 * 32 * 2048) return;
    int s = idx & 2047;
    int hv = (idx >> 11) & 31;
    int b = idx >> 16;
    int gg = hv & 1, hk = hv >> 1;
    long base = ((long)b * 2048 + s) * 64 + hk * 4;
    float bv = ba[base + gg];
    float av = ba[base + 2 + gg];
    float xx = av + dt_bias[hv];
    float sp = (xx > 20.f) ? xx : log1pf(expf(xx));
    float gv = -expf(a_log[hv]) * sp;
    eg[idx] = expf(gv);
    bt[idx] = 1.f / (1.f + expf(-bv));
}

// ------------------------------------------------------------------
// sequential gated delta scan (f16 inputs, fp32 state).
// block: (b, hv, vs) — 16 state columns, 16 dk-groups of 8.
// ------------------------------------------------------------------
struct ScanLd {
    f16x8 kv, qv;
    float vv, egv, btv;
};

__global__ __launch_bounds__(256) void scan_kernel(const f16* __restrict__ qh,
                                                   const f16* __restrict__ kh,
                                                   const f16* __restrict__ vh,
                                                   const float* __restrict__ eg,
                                                   const float* __restrict__ bt,
                                                   float* __restrict__ o) {
    int bid = blockIdx.x;
    int vs = bid & 7;
    int hv = (bid >> 3) & 31;
    int b = bid >> 8;
    int tid = threadIdx.x;
    int col = tid >> 4, dkg = tid & 15;
    int vcol = vs * 16 + col;
    const f16* kp = kh + (((long)b * 16 + (hv >> 1)) * 2048) * 128 + dkg * 8;
    const f16* qp = qh + (((long)b * 16 + (hv >> 1)) * 2048) * 128 + dkg * 8;
    const f16* vp = vh + (((long)b * 32 + hv) * 2048) * 128 + vcol;
    const float* egp = eg + ((long)b * 32 + hv) * 2048;
    const float* btp = bt + ((long)b * 32 + hv) * 2048;
    float* op = o + ((long)b * 2048 * 32 + hv) * 128 + vcol;

    float St[8] = {0.f, 0.f, 0.f, 0.f, 0.f, 0.f, 0.f, 0.f};

    auto load = [&](int s) {
        ScanLd r;
        r.kv = *(const f16x8*)(kp + (long)s * 128);
        r.qv = *(const f16x8*)(qp + (long)s * 128);
        r.vv = (float)vp[(long)s * 128];
        r.egv = egp[s];
        r.btv = btp[s];
        return r;
    };
    auto step = [&](const ScanLd& L, int s) {
        float kf[8], qf[8];
#pragma unroll
        for (int i = 0; i < 8; ++i) { kf[i] = (float)L.kv[i]; qf[i] = (float)L.qv[i]; }
        float e = L.egv;
        float part = 0.f;
#pragma unroll
        for (int i = 0; i < 8; ++i) {
            St[i] *= e;
            part = fmaf(kf[i], St[i], part);
        }
        part += __shfl_xor(part, 1);
        part += __shfl_xor(part, 2);
        part += __shfl_xor(part, 4);
        part += __shfl_xor(part, 8);
        float dv = L.btv * (L.vv - part);
        float po = 0.f;
#pragma unroll
        for (int i = 0; i < 8; ++i) {
            St[i] = fmaf(kf[i], dv, St[i]);
            po = fmaf(qf[i], St[i], po);
        }
        po += __shfl_xor(po, 1);
        po += __shfl_xor(po, 2);
        po += __shfl_xor(po, 4);
        po += __shfl_xor(po, 8);
        if (dkg == 0) op[(long)s * 4096] = po;
    };

    ScanLd A = load(0);
    for (int s = 0; s < 2048; s += 2) {
        ScanLd Bv = load(s + 1);
        step(A, s);
        A = load(s + 2 < 2048 ? s + 2 : 2047);
        step(Bv, s + 1);
    }
}

// ------------------------------------------------------------------
// y = rmsnorm(o * silu(z)) * norm_w  -> f16
// ------------------------------------------------------------------
__global__ __launch_bounds__(256) void gate_kernel(const float* __restrict__ o,
                                                   const f16* __restrict__ qkvz,
                                                   const float* __restrict__ norm_w,
                                                   f16* __restrict__ y) {
    int token = blockIdx.x;  // b*2048 + s
    int tid = threadIdx.x;
    int hv = tid >> 3, part = tid & 7;
    int dv0 = part * 16;
    const float* orow = o + ((long)token * 32 + hv) * 128 + dv0;
    long zcol = (long)(hv >> 1) * 768 + 512 + (hv & 1) * 128 + dv0;
    const f16* zrow = qkvz + (long)token * 12288 + zcol;
    float yv[16];
    float ss = 0.f;
#pragma unroll
    for (int i = 0; i < 16; ++i) {
        float ov = orow[i];
        float zv = (float)zrow[i];
        float gt = zv / (1.f + expf(-zv));
        float v = ov * gt;
        yv[i] = v;
        ss += v * v;
    }
    ss += __shfl_xor(ss, 1); ss += __shfl_xor(ss, 2); ss += __shfl_xor(ss, 4);
    float scale = rsqrtf(ss * (1.f / 128.f) + 1e-6f);
    f16* yrow = y + (long)token * 4096 + hv * 128 + dv0;
#pragma unroll
    for (int i = 0; i < 16; ++i) yrow[i] = (f16)(yv[i] * scale * norm_w[dv0 + i]);
}

// ------------------------------------------------------------------
// Workspace layout (242 MB total, time-aliased by live range):
//   [0,96)    qkvz16                 (gemm1 -> gate)
//   [96,160)  x16(16)+WT(48)         (prep -> gemm1), then ob f32 (scan -> gate)
//   [160,176) WTo                    (prep -> gemm2)
//   [176,240) qh(16) kh(16) vh(32)   (conv -> scan), first 32 reused as y16 (gate -> gemm2)
//   [240,242) bab / egb / btb
// ------------------------------------------------------------------
extern "C" void kernel_launch(void* const* d_in, const int* in_sizes, int n_in,
                              void* d_out, int out_size, void* d_ws, size_t ws_size,
                              hipStream_t stream) {
    const float* x       = (const float*)d_in[0];
    const float* w_qkvz  = (const float*)d_in[1];
    const float* w_ba    = (const float*)d_in[2];
    const float* conv_w  = (const float*)d_in[3];
    const float* conv_b  = (const float*)d_in[4];
    const float* a_log   = (const float*)d_in[5];
    const float* dt_bias = (const float*)d_in[6];
    const float* norm_w  = (const float*)d_in[7];
    const float* w_o     = (const float*)d_in[8];
    float* out = (float*)d_out;

    char* ws = (char*)d_ws;
    const size_t MB = 1024 * 1024;
    f16*   qkvz16 = (f16*)ws;                      // 96 MB
    f16*   x16    = (f16*)(ws + 96 * MB);          // 16 MB  } aliased by ob
    f16*   WT     = (f16*)(ws + 112 * MB);         // 48 MB  }
    float* ob     = (float*)(ws + 96 * MB);        // 64 MB (after gemm1)
    f16*   WTo    = (f16*)(ws + 160 * MB);         // 16 MB
    f16*   qh     = (f16*)(ws + 176 * MB);         // 16 MB  } first 32 MB aliased by y16
    f16*   kh     = (f16*)(ws + 192 * MB);         // 16 MB  }
    f16*   vh     = (f16*)(ws + 208 * MB);         // 32 MB
    f16*   y16    = (f16*)(ws + 176 * MB);         // 32 MB (after scan)
    float* bab    = (float*)(ws + 240 * MB);       // 1 MB
    float* egb    = (float*)(ws + 241 * MB);       // 0.5 MB
    float* btb    = (float*)(ws + 241 * MB + 512 * 1024);  // 0.5 MB

    // prep: convert / transpose weights & activations
    cvt16_kernel<<<8192, 256, 0, stream>>>(x, x16, 4096 * 2048 / 4);
    transpose16_kernel<<<dim3(12288 / 64, 2048 / 64), 256, 0, stream>>>(w_qkvz, WT, 2048, 12288);
    transpose16_kernel<<<dim3(2048 / 64, 4096 / 64), 256, 0, stream>>>(w_o, WTo, 4096, 2048);

    // qkvz = x @ w_qkvz   (f16 MFMA, f16 out)
    gemm16_kernel<1><<<dim3(12288 / 128, 4096 / 128), 256, 0, stream>>>(x16, WT, qkvz16, 4096, 12288, 2048);
    // ba = x @ w_ba (fp32)
    ba_gemm_kernel<<<256, 256, 0, stream>>>(x, w_ba, bab);

    // conv + silu + l2norm  (f16 out)
    conv_kernel<<<dim3(64, 64, 2), 256, 0, stream>>>(qkvz16, conv_w, conv_b, qh, kh, vh);
    // gate scalars
    gb_kernel<<<512, 256, 0, stream>>>(bab, a_log, dt_bias, egb, btb);

    // sequential delta-rule scan (writes ob over dead x16/WT)
    scan_kernel<<<512, 256, 0, stream>>>(qh, kh, vh, egb, btb, ob);

    // gating + rmsnorm -> y16 (over dead qh/kh)
    gate_kernel<<<4096, 256, 0, stream>>>(ob, qkvz16, norm_w, y16);

    // out = y @ w_o  (f16 MFMA, f32 out)
    gemm16_kernel<0><<<dim3(2048 / 128, 4096 / 128), 256, 0, stream>>>(y16, WTo, out, 4096, 2048, 4096);
}

// Round 3
// 1213.750 us; speedup vs baseline: 1.3406x; 1.3406x over previous
//
#include <hip/hip_runtime.h>

typedef _Float16 f16;
typedef _Float16 f16x4 __attribute__((ext_vector_type(4)));
typedef _Float16 f16x8 __attribute__((ext_vector_type(8)));
typedef float f32x4 __attribute__((ext_vector_type(4)));

#define QSCALE 0.08838834764831845f  // DK^-0.5

// ------------------------------------------------------------------
// convert fp32 -> f16 (vectorized x4)
// ------------------------------------------------------------------
__global__ __launch_bounds__(256) void cvt16_kernel(const float* __restrict__ in,
                                                    f16* __restrict__ out, int n4) {
    int i = blockIdx.x * 256 + threadIdx.x;
    if (i >= n4) return;
    f32x4 v = ((const f32x4*)in)[i];
    f16x4 h;
    h[0] = (f16)v[0]; h[1] = (f16)v[1]; h[2] = (f16)v[2]; h[3] = (f16)v[3];
    ((f16x4*)out)[i] = h;
}

// ------------------------------------------------------------------
// transpose fp32 [R][C] -> f16 [C][R]
// ------------------------------------------------------------------
__global__ __launch_bounds__(256) void transpose16_kernel(const float* __restrict__ in,
                                                          f16* __restrict__ out, int R, int C) {
    __shared__ f16 tile[64][66];
    int c0 = blockIdx.x * 64, r0 = blockIdx.y * 64;
    int tid = threadIdx.x;
#pragma unroll
    for (int i = 0; i < 16; ++i) {
        int idx = i * 256 + tid;
        int r = idx >> 6, c = idx & 63;
        tile[r][c] = (f16)in[(long)(r0 + r) * C + (c0 + c)];
    }
    __syncthreads();
#pragma unroll
    for (int i = 0; i < 16; ++i) {
        int idx = i * 256 + tid;
        int orow = idx >> 6, oc = idx & 63;
        out[(long)(c0 + orow) * R + (r0 + oc)] = tile[oc][orow];
    }
}

// ------------------------------------------------------------------
// f16 MFMA GEMM: C[m][n] = sum_k A[m][k] * Bt[n][k]
// 128x128 tile, BK=64, 4 waves (2x2), XOR-swizzled LDS, reg-staged.
// ------------------------------------------------------------------
template <int F16OUT>
__global__ __launch_bounds__(256) void gemm16_kernel(const f16* __restrict__ A,
                                                     const f16* __restrict__ Bt,
                                                     void* __restrict__ Cout,
                                                     int M, int N, int Kd) {
    __shared__ f16 sA[128 * 64];
    __shared__ f16 sB[128 * 64];
    const int tid = threadIdx.x;
    const int lane = tid & 63, wv = tid >> 6;
    const int wm = wv >> 1, wn = wv & 1;
    const int m0 = blockIdx.y * 128, n0 = blockIdx.x * 128;
    const int lrow = lane & 15, lk = lane >> 4;
    f32x4 acc[4][4] = {};
    for (int k0 = 0; k0 < Kd; k0 += 64) {
        __syncthreads();
#pragma unroll
        for (int j = 0; j < 4; ++j) {
            int P = (tid + j * 256) * 16;
            int row = P >> 7;
            int sw = P ^ ((row & 7) << 4);
            int koff = P & 127;
            const char* ga = (const char*)(A + (long)(m0 + row) * Kd + k0) + koff;
            *(f32x4*)((char*)sA + sw) = *(const f32x4*)ga;
            const char* gb = (const char*)(Bt + (long)(n0 + row) * Kd + k0) + koff;
            *(f32x4*)((char*)sB + sw) = *(const f32x4*)gb;
        }
        __syncthreads();
#pragma unroll
        for (int kk = 0; kk < 2; ++kk) {
            f16x8 af[4], bf[4];
#pragma unroll
            for (int i = 0; i < 4; ++i) {
                int arow = wm * 64 + i * 16 + lrow;
                int abyte = arow * 128 + kk * 64 + lk * 16;
                af[i] = *(const f16x8*)((const char*)sA + (abyte ^ ((arow & 7) << 4)));
                int brow = wn * 64 + i * 16 + lrow;
                int bbyte = brow * 128 + kk * 64 + lk * 16;
                bf[i] = *(const f16x8*)((const char*)sB + (bbyte ^ ((brow & 7) << 4)));
            }
#pragma unroll
            for (int i = 0; i < 4; ++i)
#pragma unroll
                for (int j = 0; j < 4; ++j)
                    acc[i][j] = __builtin_amdgcn_mfma_f32_16x16x32_f16(af[i], bf[j], acc[i][j], 0, 0, 0);
        }
    }
#pragma unroll
    for (int i = 0; i < 4; ++i) {
        int gm_base = m0 + wm * 64 + i * 16 + lk * 4;
#pragma unroll
        for (int j = 0; j < 4; ++j) {
            int gn = n0 + wn * 64 + j * 16 + lrow;
#pragma unroll
            for (int r = 0; r < 4; ++r) {
                long idx = (long)(gm_base + r) * N + gn;
                if (F16OUT) ((f16*)Cout)[idx] = (f16)acc[i][j][r];
                else        ((float*)Cout)[idx] = acc[i][j][r];
            }
        }
    }
}

// ------------------------------------------------------------------
// ba = x @ w_ba   (fp32)
// ------------------------------------------------------------------
__global__ __launch_bounds__(256) void ba_gemm_kernel(const float* __restrict__ x,
                                                      const float* __restrict__ w,
                                                      float* __restrict__ ba) {
    __shared__ float xs[16][256];
    int tid = threadIdx.x;
    int t0 = blockIdx.x * 16;
    int o = tid & 63, tg = tid >> 6;
    float acc[4] = {0.f, 0.f, 0.f, 0.f};
    for (int kc = 0; kc < 2048; kc += 256) {
        __syncthreads();
#pragma unroll
        for (int i = 0; i < 16; ++i) {
            int idx = i * 256 + tid;
            int tok = idx >> 8, k = idx & 255;
            xs[tok][k] = x[(long)(t0 + tok) * 2048 + kc + k];
        }
        __syncthreads();
        for (int k = 0; k < 256; ++k) {
            float wv = w[(long)(kc + k) * 64 + o];
#pragma unroll
            for (int j = 0; j < 4; ++j) acc[j] += xs[tg * 4 + j][k] * wv;
        }
    }
#pragma unroll
    for (int j = 0; j < 4; ++j) ba[(long)(t0 + tg * 4 + j) * 64 + o] = acc[j];
}

// ------------------------------------------------------------------
// depthwise causal conv(K=4) + bias + SiLU (+ L2norm for q/k heads)
// ------------------------------------------------------------------
__global__ __launch_bounds__(256) void conv_kernel(const f16* __restrict__ qkvz,
                                                   const float* __restrict__ cw,
                                                   const float* __restrict__ cb,
                                                   f16* __restrict__ qh,
                                                   f16* __restrict__ kh,
                                                   f16* __restrict__ vh) {
    __shared__ float Lin[35 * 128];
    __shared__ float Lout[32 * 128];
    __shared__ float Lsc[32];
    int g = blockIdx.x;
    int s0 = blockIdx.y * 32;
    int b = blockIdx.z;
    int tid = threadIdx.x;
    int colbase, chbase;
    f16* outp;
    bool donorm;
    float nmul;
    if (g < 16) {
        colbase = g * 768; chbase = g * 128;
        outp = qh + (((long)b * 16 + g) * 2048 + s0) * 128;
        donorm = true; nmul = QSCALE;
    } else if (g < 32) {
        int hk = g - 16;
        colbase = hk * 768 + 128; chbase = 2048 + hk * 128;
        outp = kh + (((long)b * 16 + hk) * 2048 + s0) * 128;
        donorm = true; nmul = 1.f;
    } else {
        int hv = g - 32;
        colbase = (hv >> 1) * 768 + 256 + (hv & 1) * 128; chbase = 4096 + hv * 128;
        outp = vh + (((long)b * 32 + hv) * 2048 + s0) * 128;
        donorm = false; nmul = 1.f;
    }
    for (int idx = tid; idx < 35 * 128; idx += 256) {
        int sr = idx >> 7, c = idx & 127;
        int s = s0 + sr - 3;
        Lin[idx] = (s >= 0) ? (float)qkvz[((long)b * 2048 + s) * 12288 + colbase + c] : 0.f;
    }
    __syncthreads();
    int c = tid & 127, sg = tid >> 7;
    float w0 = cw[(chbase + c) * 4 + 0];
    float w1 = cw[(chbase + c) * 4 + 1];
    float w2 = cw[(chbase + c) * 4 + 2];
    float w3 = cw[(chbase + c) * 4 + 3];
    float bias = cb[chbase + c];
#pragma unroll
    for (int j = 0; j < 16; ++j) {
        int sl = sg * 16 + j;
        float v = w0 * Lin[sl * 128 + c] + w1 * Lin[(sl + 1) * 128 + c] +
                  w2 * Lin[(sl + 2) * 128 + c] + w3 * Lin[(sl + 3) * 128 + c] + bias;
        v = v / (1.f + expf(-v));  // SiLU
        Lout[sl * 128 + c] = v;
    }
    __syncthreads();
    if (donorm) {
        int token = tid >> 3, part = tid & 7;
        float ss = 0.f;
#pragma unroll
        for (int i = 0; i < 16; ++i) {
            float v = Lout[token * 128 + part * 16 + i];
            ss += v * v;
        }
        ss += __shfl_xor(ss, 1); ss += __shfl_xor(ss, 2); ss += __shfl_xor(ss, 4);
        if (part == 0) Lsc[token] = rsqrtf(ss + 1e-6f) * nmul;
        __syncthreads();
#pragma unroll
        for (int j = 0; j < 16; ++j) {
            int sl = sg * 16 + j;
            outp[(long)sl * 128 + c] = (f16)(Lout[sl * 128 + c] * Lsc[sl]);
        }
    } else {
#pragma unroll
        for (int j = 0; j < 16; ++j) {
            int sl = sg * 16 + j;
            outp[(long)sl * 128 + c] = (f16)Lout[sl * 128 + c];
        }
    }
}

// ------------------------------------------------------------------
// eg = exp(g), beta = sigmoid(b)
// ------------------------------------------------------------------
__global__ __launch_bounds__(256) void gb_kernel(const float* __restrict__ ba,
                                                 const float* __restrict__ a_log,
                                                 const float* __restrict__ dt_bias,
                                                 float* __restrict__ eg,
                                                 float* __restrict__ bt) {
    int idx = blockIdx.x * 256 + threadIdx.x;  // ((b*32+hv)*2048 + s)
    if (idx >= 2 * 32 * 2048) return;
    int s = idx & 2047;
    int hv = (idx >> 11) & 31;
    int b = idx >> 16;
    int gg = hv & 1, hk = hv >> 1;
    long base = ((long)b * 2048 + s) * 64 + hk * 4;
    float bv = ba[base + gg];
    float av = ba[base + 2 + gg];
    float xx = av + dt_bias[hv];
    float sp = (xx > 20.f) ? xx : log1pf(expf(xx));
    float gv = -expf(a_log[hv]) * sp;
    eg[idx] = expf(gv);
    bt[idx] = 1.f / (1.f + expf(-bv));
}

// ------------------------------------------------------------------
// sum across a DPP row of 16 lanes (our dkg group) via row_ror adds
// ------------------------------------------------------------------
__device__ __forceinline__ float rowsum16(float x) {
    int v;
    v = __float_as_int(x);
    x += __int_as_float(__builtin_amdgcn_update_dpp(v, v, 0x121, 0xF, 0xF, false));  // row_ror:1
    v = __float_as_int(x);
    x += __int_as_float(__builtin_amdgcn_update_dpp(v, v, 0x122, 0xF, 0xF, false));  // row_ror:2
    v = __float_as_int(x);
    x += __int_as_float(__builtin_amdgcn_update_dpp(v, v, 0x124, 0xF, 0xF, false));  // row_ror:4
    v = __float_as_int(x);
    x += __int_as_float(__builtin_amdgcn_update_dpp(v, v, 0x128, 0xF, 0xF, false));  // row_ror:8
    return x;
}

// ------------------------------------------------------------------
// sequential gated delta scan, chunked LDS staging.
// block: 512 threads = 32 cols x 16 dkg; grid 256 = (b, hv, vs in [0,4))
// fp32 state (8 per thread); f16 k/q/v inputs.
// ------------------------------------------------------------------
#define CH 32  // steps per staged chunk

struct StepRegs {
    f16x8 k, q;
    float v, e, b;
};

__global__ __launch_bounds__(512) void scan_kernel(const f16* __restrict__ qh,
                                                   const f16* __restrict__ kh,
                                                   const f16* __restrict__ vh,
                                                   const float* __restrict__ eg,
                                                   const float* __restrict__ bt,
                                                   float* __restrict__ o) {
    __shared__ f16 Lk[CH * 128];
    __shared__ f16 Lq[CH * 128];
    __shared__ f16 Lv[CH * 32];
    __shared__ float Leg[CH];
    __shared__ float Lbt[CH];

    int bid = blockIdx.x;
    int vs = bid & 3;
    int hv = (bid >> 2) & 31;
    int b = bid >> 7;
    int tid = threadIdx.x;
    int col = tid >> 4, dkg = tid & 15;
    int vcol = vs * 32 + col;
    const f16* kp = kh + ((long)b * 16 + (hv >> 1)) * 2048 * 128;
    const f16* qp = qh + ((long)b * 16 + (hv >> 1)) * 2048 * 128;
    const f16* vp = vh + ((long)b * 32 + hv) * 2048 * 128;
    const float* egp = eg + ((long)b * 32 + hv) * 2048;
    const float* btp = bt + ((long)b * 32 + hv) * 2048;
    float* op = o + ((long)b * 2048 * 32 + hv) * 128 + vcol;

    // staging registers (chunk of CH steps, cooperatively loaded)
    f16x8 rk, rq, rv;
    float re = 0.f, rb = 0.f;
    const int vstep = tid >> 2, vpart = tid & 3;  // for v staging (tid<128)

    auto issue_loads = [&](int c) {
        long base = (long)c * CH * 128;
        rk = *(const f16x8*)(kp + base + tid * 8);
        rq = *(const f16x8*)(qp + base + tid * 8);
        if (tid < 128) rv = *(const f16x8*)(vp + base + vstep * 128 + vs * 32 + vpart * 8);
        if (tid < CH) re = egp[c * CH + tid];
        else if (tid < 2 * CH) rb = btp[c * CH + (tid - CH)];
    };
    auto commit = [&]() {
        *(f16x8*)(Lk + tid * 8) = rk;
        *(f16x8*)(Lq + tid * 8) = rq;
        if (tid < 128) *(f16x8*)(Lv + vstep * 32 + vpart * 8) = rv;
        if (tid < CH) Leg[tid] = re;
        else if (tid < 2 * CH) Lbt[tid - CH] = rb;
    };

    float St[8] = {0.f, 0.f, 0.f, 0.f, 0.f, 0.f, 0.f, 0.f};

    auto lds_ld = [&](int s, StepRegs& r) {
        r.k = *(const f16x8*)(Lk + s * 128 + dkg * 8);
        r.q = *(const f16x8*)(Lq + s * 128 + dkg * 8);
        r.v = (float)Lv[s * 32 + col];
        r.e = Leg[s];
        r.b = Lbt[s];
    };
    auto do_step = [&](const StepRegs& L, int s) {
        float kf[8], qf[8];
#pragma unroll
        for (int i = 0; i < 8; ++i) { kf[i] = (float)L.k[i]; qf[i] = (float)L.q[i]; }
        float e = L.e;
        float part = 0.f;
#pragma unroll
        for (int i = 0; i < 8; ++i) {
            St[i] *= e;
            part = fmaf(kf[i], St[i], part);
        }
        part = rowsum16(part);
        float dv = L.b * (L.v - part);
        float po = 0.f;
#pragma unroll
        for (int i = 0; i < 8; ++i) {
            St[i] = fmaf(kf[i], dv, St[i]);
            po = fmaf(qf[i], St[i], po);
        }
        po = rowsum16(po);
        if (dkg == 0) op[(long)s * 4096] = po;
    };

    // prologue: stage chunk 0
    issue_loads(0);
    commit();
    __syncthreads();

    for (int c = 0; c < 2048 / CH; ++c) {
        if (c + 1 < 2048 / CH) issue_loads(c + 1);  // in flight during compute
        StepRegs A, Bv;
        lds_ld(0, A);
        for (int s = 0; s < CH; s += 2) {
            lds_ld(s + 1, Bv);
            do_step(A, c * CH + s);
            if (s + 2 < CH) lds_ld(s + 2, A);
            do_step(Bv, c * CH + s + 1);
        }
        __syncthreads();  // all waves done reading LDS
        if (c + 1 < 2048 / CH) commit();
        __syncthreads();
    }
}

// ------------------------------------------------------------------
// y = rmsnorm(o * silu(z)) * norm_w  -> f16
// ------------------------------------------------------------------
__global__ __launch_bounds__(256) void gate_kernel(const float* __restrict__ o,
                                                   const f16* __restrict__ qkvz,
                                                   const float* __restrict__ norm_w,
                                                   f16* __restrict__ y) {
    int token = blockIdx.x;  // b*2048 + s
    int tid = threadIdx.x;
    int hv = tid >> 3, part = tid & 7;
    int dv0 = part * 16;
    const float* orow = o + ((long)token * 32 + hv) * 128 + dv0;
    long zcol = (long)(hv >> 1) * 768 + 512 + (hv & 1) * 128 + dv0;
    const f16* zrow = qkvz + (long)token * 12288 + zcol;
    float yv[16];
    float ss = 0.f;
#pragma unroll
    for (int i = 0; i < 16; ++i) {
        float ov = orow[i];
        float zv = (float)zrow[i];
        float gt = zv / (1.f + expf(-zv));
        float v = ov * gt;
        yv[i] = v;
        ss += v * v;
    }
    ss += __shfl_xor(ss, 1); ss += __shfl_xor(ss, 2); ss += __shfl_xor(ss, 4);
    float scale = rsqrtf(ss * (1.f / 128.f) + 1e-6f);
    f16* yrow = y + (long)token * 4096 + hv * 128 + dv0;
#pragma unroll
    for (int i = 0; i < 16; ++i) yrow[i] = (f16)(yv[i] * scale * norm_w[dv0 + i]);
}

// ------------------------------------------------------------------
// Workspace layout (242 MB total, time-aliased by live range):
//   [0,96)    qkvz16                 (gemm1 -> gate)
//   [96,160)  x16(16)+WT(48)         (prep -> gemm1), then ob f32 (scan -> gate)
//   [160,176) WTo                    (prep -> gemm2)
//   [176,240) qh(16) kh(16) vh(32)   (conv -> scan), first 32 reused as y16 (gate -> gemm2)
//   [240,242) bab / egb / btb
// ------------------------------------------------------------------
extern "C" void kernel_launch(void* const* d_in, const int* in_sizes, int n_in,
                              void* d_out, int out_size, void* d_ws, size_t ws_size,
                              hipStream_t stream) {
    const float* x       = (const float*)d_in[0];
    const float* w_qkvz  = (const float*)d_in[1];
    const float* w_ba    = (const float*)d_in[2];
    const float* conv_w  = (const float*)d_in[3];
    const float* conv_b  = (const float*)d_in[4];
    const float* a_log   = (const float*)d_in[5];
    const float* dt_bias = (const float*)d_in[6];
    const float* norm_w  = (const float*)d_in[7];
    const float* w_o     = (const float*)d_in[8];
    float* out = (float*)d_out;

    char* ws = (char*)d_ws;
    const size_t MB = 1024 * 1024;
    f16*   qkvz16 = (f16*)ws;                      // 96 MB
    f16*   x16    = (f16*)(ws + 96 * MB);          // 16 MB  } aliased by ob
    f16*   WT     = (f16*)(ws + 112 * MB);         // 48 MB  }
    float* ob     = (float*)(ws + 96 * MB);        // 64 MB (after gemm1)
    f16*   WTo    = (f16*)(ws + 160 * MB);         // 16 MB
    f16*   qh     = (f16*)(ws + 176 * MB);         // 16 MB  } first 32 MB aliased by y16
    f16*   kh     = (f16*)(ws + 192 * MB);         // 16 MB  }
    f16*   vh     = (f16*)(ws + 208 * MB);         // 32 MB
    f16*   y16    = (f16*)(ws + 176 * MB);         // 32 MB (after scan)
    float* bab    = (float*)(ws + 240 * MB);       // 1 MB
    float* egb    = (float*)(ws + 241 * MB);       // 0.5 MB
    float* btb    = (float*)(ws + 241 * MB + 512 * 1024);  // 0.5 MB

    // prep: convert / transpose weights & activations
    cvt16_kernel<<<8192, 256, 0, stream>>>(x, x16, 4096 * 2048 / 4);
    transpose16_kernel<<<dim3(12288 / 64, 2048 / 64), 256, 0, stream>>>(w_qkvz, WT, 2048, 12288);
    transpose16_kernel<<<dim3(2048 / 64, 4096 / 64), 256, 0, stream>>>(w_o, WTo, 4096, 2048);

    // qkvz = x @ w_qkvz   (f16 MFMA, f16 out)
    gemm16_kernel<1><<<dim3(12288 / 128, 4096 / 128), 256, 0, stream>>>(x16, WT, qkvz16, 4096, 12288, 2048);
    // ba = x @ w_ba (fp32)
    ba_gemm_kernel<<<256, 256, 0, stream>>>(x, w_ba, bab);

    // conv + silu + l2norm  (f16 out)
    conv_kernel<<<dim3(64, 64, 2), 256, 0, stream>>>(qkvz16, conv_w, conv_b, qh, kh, vh);
    // gate scalars
    gb_kernel<<<512, 256, 0, stream>>>(bab, a_log, dt_bias, egb, btb);

    // sequential delta-rule scan (writes ob over dead x16/WT)
    scan_kernel<<<256, 512, 0, stream>>>(qh, kh, vh, egb, btb, ob);

    // gating + rmsnorm -> y16 (over dead qh/kh)
    gate_kernel<<<4096, 256, 0, stream>>>(ob, qkvz16, norm_w, y16);

    // out = y @ w_o  (f16 MFMA, f32 out)
    gemm16_kernel<0><<<dim3(2048 / 128, 4096 / 128), 256, 0, stream>>>(y16, WTo, out, 4096, 2048, 4096);
}